// Round 1
// 1577.185 us; speedup vs baseline: 1.5669x; 1.5669x over previous
//
#include <hip/hip_runtime.h>
#include <math.h>

// QuantumAttention. B=2 S=2048 H=1024 NH=16 DH=64.
// Output = normed(4.19M) ++ probs(134.2M) fp32.
// This rev: k_scores moved to bf16 hi/lo-split MFMA (fp32-equivalent numerics,
// ~2^-17 operand error). K1 emits q/k as packed [hi(64)|lo(64)] bf16 rows.
// Workspace (floats): qrP | qiP | krP | kiP (bf16 hi/lo, NELEM floats each)
//                     | vm (fp32) | lsum  -> 5*4194304 + 65536 floats = 84.2 MB.
// K2 stores e=exp(score) into probs region; K3 normalizes p = e * rinv.

#define B_  2
#define S_  2048
#define H_  1024
#define NH_ 16
#define DH_ 64
#define NELEM    4194304   // B*NH*S*DH
#define NORMEDSZ 4194304   // B*S*H

typedef __attribute__((ext_vector_type(8))) short bf16x8;
typedef __attribute__((ext_vector_type(4))) float f32x4;

__device__ __forceinline__ ushort f2bf(float x) {   // RNE truncate to bf16
  uint u = __float_as_uint(x);
  u += 0x7fffu + ((u >> 16) & 1u);
  return (ushort)(u >> 16);
}
__device__ __forceinline__ float bf2f(ushort h) {
  return __uint_as_float(((uint)h) << 16);
}

// ---------------------------------------------------------------------------
// K1: per (b, h, 32-token tile): c = x@W+b ; (r,i)/=|.| ; complex rotate by U.
// q/k results written as bf16 hi/lo pairs (row layout [hi 64 | lo 64]); |v| fp32.
// ---------------------------------------------------------------------------
__global__ __launch_bounds__(256, 4) void k_prep_gate(
    const float* __restrict__ hidden,
    const float* __restrict__ Wq, const float* __restrict__ bq,
    const float* __restrict__ Wk, const float* __restrict__ bk,
    const float* __restrict__ Wv, const float* __restrict__ bv,
    const float* __restrict__ Uqr, const float* __restrict__ Uqi,
    const float* __restrict__ Ukr, const float* __restrict__ Uki,
    const float* __restrict__ Uvr, const float* __restrict__ Uvi,
    ushort* __restrict__ qrP, ushort* __restrict__ qiP,
    ushort* __restrict__ krP, ushort* __restrict__ kiP,
    float* __restrict__ vm)
{
  const int bid = blockIdx.x;          // 2*16*64 = 2048 blocks
  const int st  = bid & 63;
  const int h   = (bid >> 6) & 15;
  const int b   = bid >> 10;
  const int s0  = st * 32;
  const int tid = threadIdx.x;
  const int j   = tid & 63;
  const int tg  = tid >> 6;            // wave id: uniform -> LDS broadcast reads

  __shared__ float xs[32][64];
  __shared__ float rb[32][64];
  __shared__ float ib[32][64];

  for (int i = 0; i < 8; ++i) {
    int f = tid + i * 256;
    int t = f >> 6, d = f & 63;
    xs[t][d] = hidden[((b * S_ + s0 + t) * H_) + h * 64 + d];
  }
  __syncthreads();

  const float* Ws[3]  = {Wq, Wk, Wv};
  const float* bs[3]  = {bq, bk, bv};
  const float* Urs[3] = {Uqr, Ukr, Uvr};
  const float* Uis[3] = {Uqi, Uki, Uvi};
  const int bh   = b * NH_ + h;
  const int head = bh * S_ * DH_;

  for (int m = 0; m < 3; ++m) {
    const float* W  = Ws[m];
    const float* bb = bs[m];
    const float* Ur = Urs[m];
    const float* Ui = Uis[m];

    float cr[8], ci[8];
    const float bj0 = bb[j], bj1 = bb[64 + j];
#pragma unroll
    for (int p = 0; p < 8; ++p) { cr[p] = bj0; ci[p] = bj1; }
    for (int d = 0; d < 64; ++d) {
      float wr = W[d * 128 + j];
      float wi = W[d * 128 + 64 + j];
#pragma unroll
      for (int p = 0; p < 8; ++p) {
        float x = xs[tg * 8 + p][d];
        cr[p] = fmaf(x, wr, cr[p]);
        ci[p] = fmaf(x, wi, ci[p]);
      }
    }
#pragma unroll
    for (int p = 0; p < 8; ++p) {
      float inv = rsqrtf(cr[p] * cr[p] + ci[p] * ci[p] + 1e-12f);
      rb[tg * 8 + p][j] = cr[p] * inv;
      ib[tg * 8 + p][j] = ci[p] * inv;
    }
    __syncthreads();

    float gr[8] = {0.f,0.f,0.f,0.f,0.f,0.f,0.f,0.f};
    float gi[8] = {0.f,0.f,0.f,0.f,0.f,0.f,0.f,0.f};
    for (int d = 0; d < 64; ++d) {
      float ur = Ur[d * 64 + j];
      float ui = Ui[d * 64 + j];
#pragma unroll
      for (int p = 0; p < 8; ++p) {
        float rv = rb[tg * 8 + p][d];
        float iv = ib[tg * 8 + p][d];
        gr[p] = fmaf(rv, ur, fmaf(-iv, ui, gr[p]));
        gi[p] = fmaf(rv, ui, fmaf( iv, ur, gi[p]));
      }
    }
    if (m == 2) {
#pragma unroll
      for (int p = 0; p < 8; ++p) {
        int t = tg * 8 + p;
        vm[head + (s0 + t) * DH_ + j] = sqrtf(gr[p] * gr[p] + gi[p] * gi[p]);
      }
    } else {
      ushort* R = (m == 0) ? qrP : krP;
      ushort* I = (m == 0) ? qiP : kiP;
#pragma unroll
      for (int p = 0; p < 8; ++p) {
        int t = tg * 8 + p;
        size_t pb = (((size_t)bh) * S_ + (s0 + t)) * 128 + j;
        ushort hr = f2bf(gr[p]);
        R[pb]      = hr;
        R[pb + 64] = f2bf(gr[p] - bf2f(hr));
        ushort hi2 = f2bf(gi[p]);
        I[pb]      = hi2;
        I[pb + 64] = f2bf(gi[p] - bf2f(hi2));
      }
    }
    __syncthreads();  // rb/ib reused next stage
  }
}

// ---------------------------------------------------------------------------
// K2: complex QK^T via bf16 hi/lo MFMA (K=128 contraction per product pair),
// epilogue |.|*scale -> threshold -> e = exp(m) stored to probs region,
// per-row sum of e -> lsum. Block = 64q x all-k loop; 4 waves 2x2, each wave
// 32x32 out via 16x16x32 mfma, 4 accumulator sets (rr, ii, ri, ir).
// K tile [64 keys][128 d] bf16 in LDS, XOR-swizzled (byte ^= (key&7)<<4).
// ---------------------------------------------------------------------------
#define MFMA16 __builtin_amdgcn_mfma_f32_16x16x32_bf16

__global__ __launch_bounds__(256, 2) void k_scores_mfma(
    const ushort* __restrict__ qrP, const ushort* __restrict__ qiP,
    const ushort* __restrict__ krP, const ushort* __restrict__ kiP,
    float* __restrict__ praw, float* __restrict__ lsum)
{
  // XCD-bijective swizzle: 1024 blocks -> 8 chunks of 128 (nwg % 8 == 0).
  const int bid0 = blockIdx.x;
  const int bid  = (bid0 & 7) * 128 + (bid0 >> 3);
  const int qt = bid & 31;
  const int bh = bid >> 5;
  const int q0 = qt * 64;
  const int tid  = threadIdx.x;
  const int lane = tid & 63;
  const int w    = tid >> 6;           // 4 waves
  const int wq   = w & 1;              // q half (32 rows)
  const int wk   = w >> 1;             // k half (32 cols)
  const int l15  = lane & 15;
  const int lg   = lane >> 4;          // 0..3

  __shared__ __align__(16) ushort skr[64 * 128];
  __shared__ __align__(16) ushort ski[64 * 128];
  __shared__ float lsh[64];
  if (tid < 64) lsh[tid] = 0.f;

  // Q fragments persistent in registers: rows q0+wq*32+rt*16+l15, d = ks*32+lg*8
  bf16x8 aqr[2][4], aqi[2][4];
#pragma unroll
  for (int rt = 0; rt < 2; ++rt) {
    const size_t ro = ((size_t)bh * S_ + q0 + wq * 32 + rt * 16 + l15) * 128 + lg * 8;
#pragma unroll
    for (int ks = 0; ks < 4; ++ks) {
      aqr[rt][ks] = *(const bf16x8*)(qrP + ro + ks * 32);
      aqi[rt][ks] = *(const bf16x8*)(qiP + ro + ks * 32);
    }
  }

  float esum[2][4] = {{0.f,0.f,0.f,0.f},{0.f,0.f,0.f,0.f}};

  const int swz = (l15 & 7) << 4;
  const int kbB = (wk * 32 + l15) * 256;   // LDS byte base of this lane's key row

  for (int kt = 0; kt < 32; ++kt) {
    __syncthreads();
    {   // stage kr/ki tile (64 keys x 128 d bf16 = 16KB each), swizzled
      const uint4* gr4 = (const uint4*)(krP + ((size_t)bh * S_ + kt * 64) * 128);
      const uint4* gi4 = (const uint4*)(kiP + ((size_t)bh * S_ + kt * 64) * 128);
#pragma unroll
      for (int i = 0; i < 4; ++i) {
        int c   = tid + i * 256;           // 1024 16B chunks
        int key = c >> 4;
        int dq  = c & 15;
        int dst = (key * 256 + dq * 16) ^ ((key & 7) << 4);
        *(uint4*)((char*)skr + dst) = gr4[c];
        *(uint4*)((char*)ski + dst) = gi4[c];
      }
    }
    __syncthreads();

    f32x4 aRR[2][2], aII[2][2], aRI[2][2], aIR[2][2];
#pragma unroll
    for (int rt = 0; rt < 2; ++rt)
#pragma unroll
      for (int ct = 0; ct < 2; ++ct) {
        aRR[rt][ct] = (f32x4){0.f,0.f,0.f,0.f};
        aII[rt][ct] = (f32x4){0.f,0.f,0.f,0.f};
        aRI[rt][ct] = (f32x4){0.f,0.f,0.f,0.f};
        aIR[rt][ct] = (f32x4){0.f,0.f,0.f,0.f};
      }

#pragma unroll
    for (int ks = 0; ks < 4; ++ks) {
#pragma unroll
      for (int ct = 0; ct < 2; ++ct) {
        const int o = kbB + ct * 4096 + ((ks * 64 + lg * 16) ^ swz);
        bf16x8 br = *(const bf16x8*)((const char*)skr + o);
        bf16x8 bi = *(const bf16x8*)((const char*)ski + o);
#pragma unroll
        for (int rt = 0; rt < 2; ++rt) {
          aRR[rt][ct] = MFMA16(aqr[rt][ks], br, aRR[rt][ct], 0, 0, 0);
          aIR[rt][ct] = MFMA16(aqi[rt][ks], br, aIR[rt][ct], 0, 0, 0);
          aRI[rt][ct] = MFMA16(aqr[rt][ks], bi, aRI[rt][ct], 0, 0, 0);
          aII[rt][ct] = MFMA16(aqi[rt][ks], bi, aII[rt][ct], 0, 0, 0);
        }
      }
    }

    // epilogue: sr/si -> |.|*0.125 -> threshold -> e = exp(m); store e
    const size_t rowb = ((size_t)bh * S_ + q0 + wq * 32) * S_
                      + (size_t)kt * 64 + wk * 32 + l15;
#pragma unroll
    for (int rt = 0; rt < 2; ++rt)
#pragma unroll
      for (int r = 0; r < 4; ++r) {
        const int rloc = rt * 16 + lg * 4 + r;
        float sr0 = aRR[rt][0][r] - aII[rt][0][r];
        float si0 = aRI[rt][0][r] + aIR[rt][0][r];
        float m0 = sqrtf(sr0 * sr0 + si0 * si0) * 0.125f;
        m0 = (m0 < 0.1f) ? 0.f : m0;
        float e0 = __expf(m0);
        float sr1 = aRR[rt][1][r] - aII[rt][1][r];
        float si1 = aRI[rt][1][r] + aIR[rt][1][r];
        float m1 = sqrtf(sr1 * sr1 + si1 * si1) * 0.125f;
        m1 = (m1 < 0.1f) ? 0.f : m1;
        float e1 = __expf(m1);
        praw[rowb + (size_t)rloc * S_]      = e0;
        praw[rowb + (size_t)rloc * S_ + 16] = e1;
        esum[rt][r] += e0 + e1;
      }
  }

  // reduce exp-sums: across the 16 lanes of each lg group, then across waves
#pragma unroll
  for (int rt = 0; rt < 2; ++rt)
#pragma unroll
    for (int r = 0; r < 4; ++r) {
      float v = esum[rt][r];
      v += __shfl_xor(v, 1, 64);
      v += __shfl_xor(v, 2, 64);
      v += __shfl_xor(v, 4, 64);
      v += __shfl_xor(v, 8, 64);
      if (l15 == 0) atomicAdd(&lsh[wq * 32 + rt * 16 + lg * 4 + r], v);
    }
  __syncthreads();
  if (tid < 64) lsum[(size_t)bh * S_ + q0 + tid] = lsh[tid];
}

// ---------------------------------------------------------------------------
// K3: read e, p = e * (1/lsum) (same bits as before: e came from __expf),
// write normalized probs in-place, fused PV: ctx = P @ |V|  (ctx in [B,S,H]).
// ---------------------------------------------------------------------------
#define SPST 65

__global__ __launch_bounds__(256, 4) void k_pv(
    const float* __restrict__ vm, const float* __restrict__ lsum,
    float* __restrict__ probs, float* __restrict__ ctx)
{
  const int bid = blockIdx.x;          // 32 bh * 32 qtiles = 1024
  const int qt  = bid & 31;
  const int bh  = bid >> 5;
  const int q0  = qt * 64;
  const int b   = bh >> 4, h = bh & 15;
  const int tid = threadIdx.x;
  const int rg  = tid >> 4;            // rows r0 = 4*rg .. +3
  const int dg  = tid & 15;            // dims d0 = 4*dg .. +3
  const int r0  = rg * 4;
  const int d0  = dg * 4;
  const int head = bh * (S_ * DH_);

  __shared__ float sp[64 * SPST];
  __shared__ __align__(16) float svm[64 * 64];
  __shared__ float rinv[64];
  if (tid < 64) rinv[tid] = 1.f / lsum[bh * S_ + q0 + tid];

  float acc[4][4] = {{0.f,0.f,0.f,0.f},{0.f,0.f,0.f,0.f},
                     {0.f,0.f,0.f,0.f},{0.f,0.f,0.f,0.f}};

  for (int kt = 0; kt < 32; ++kt) {
    __syncthreads();
    for (int i = 0; i < 16; ++i) {     // normalize 64x64 tile, stash in LDS
      int f = tid + i * 256;
      int r = f >> 6, c = f & 63;
      size_t off = ((size_t)bh * S_ + q0 + r) * S_ + kt * 64 + c;
      float p = probs[off] * rinv[r];
      probs[off] = p;
      sp[r * SPST + c] = p;
    }
    for (int i = 0; i < 4; ++i) {      // stage |V| tile (64x64)
      int g = tid + i * 256;
      int c = g >> 4, dq = g & 15;
      *(float4*)(svm + c * 64 + dq * 4) =
          *(const float4*)(vm + head + (kt * 64 + c) * 64 + dq * 4);
    }
    __syncthreads();

    for (int ck = 0; ck < 64; ++ck) {
      const float4 v4 = *(const float4*)(svm + ck * 64 + d0);
#pragma unroll
      for (int jr = 0; jr < 4; ++jr) {
        float p = sp[(r0 + jr) * SPST + ck];
        acc[jr][0] = fmaf(p, v4.x, acc[jr][0]);
        acc[jr][1] = fmaf(p, v4.y, acc[jr][1]);
        acc[jr][2] = fmaf(p, v4.z, acc[jr][2]);
        acc[jr][3] = fmaf(p, v4.w, acc[jr][3]);
      }
    }
  }
#pragma unroll
  for (int jr = 0; jr < 4; ++jr) {
    float4 o;
    o.x = acc[jr][0]; o.y = acc[jr][1]; o.z = acc[jr][2]; o.w = acc[jr][3];
    *(float4*)(ctx + (size_t)(b * S_ + q0 + r0 + jr) * H_ + h * 64 + d0) = o;
  }
}

// ---------------------------------------------------------------------------
// K4: res = ctx @ Wo + bo + hidden   (64x64 tile, K-tile 32, 4x4 micro)
// ---------------------------------------------------------------------------
#define AST 36
#define BST 68

__global__ __launch_bounds__(256, 4) void k_out_gemm(
    const float* __restrict__ ctx, const float* __restrict__ Wo,
    const float* __restrict__ bo, const float* __restrict__ hidden,
    float* __restrict__ res)
{
  const int bid = blockIdx.x;          // 64 mtiles * 16 ntiles = 1024
  const int nt  = bid & 15;
  const int mt  = bid >> 4;
  const int m0  = mt * 64, n0 = nt * 64;
  const int tid = threadIdx.x;
  const int mg  = tid >> 4, ng = tid & 15;

  __shared__ __align__(16) float sa[64 * AST];
  __shared__ __align__(16) float sb[32 * BST];

  float acc[4][4] = {{0.f,0.f,0.f,0.f},{0.f,0.f,0.f,0.f},
                     {0.f,0.f,0.f,0.f},{0.f,0.f,0.f,0.f}};

  for (int kt = 0; kt < 32; ++kt) {
    __syncthreads();
    for (int i = 0; i < 2; ++i) {      // a tile 64x32
      int g = tid + i * 256;
      int r = g >> 3, dq = g & 7;
      *(float4*)(sa + r * AST + dq * 4) =
          *(const float4*)(ctx + (size_t)(m0 + r) * H_ + kt * 32 + dq * 4);
    }
    for (int i = 0; i < 2; ++i) {      // b tile 32x64
      int g = tid + i * 256;
      int r = g >> 4, dq = g & 15;
      *(float4*)(sb + r * BST + dq * 4) =
          *(const float4*)(Wo + (size_t)(kt * 32 + r) * H_ + n0 + dq * 4);
    }
    __syncthreads();

    for (int kk = 0; kk < 32; ++kk) {
      const float4 b4 = *(const float4*)(sb + kk * BST + ng * 4);
      const float a0 = sa[(mg * 4 + 0) * AST + kk];
      const float a1 = sa[(mg * 4 + 1) * AST + kk];
      const float a2 = sa[(mg * 4 + 2) * AST + kk];
      const float a3 = sa[(mg * 4 + 3) * AST + kk];
      acc[0][0] = fmaf(a0, b4.x, acc[0][0]); acc[0][1] = fmaf(a0, b4.y, acc[0][1]);
      acc[0][2] = fmaf(a0, b4.z, acc[0][2]); acc[0][3] = fmaf(a0, b4.w, acc[0][3]);
      acc[1][0] = fmaf(a1, b4.x, acc[1][0]); acc[1][1] = fmaf(a1, b4.y, acc[1][1]);
      acc[1][2] = fmaf(a1, b4.z, acc[1][2]); acc[1][3] = fmaf(a1, b4.w, acc[1][3]);
      acc[2][0] = fmaf(a2, b4.x, acc[2][0]); acc[2][1] = fmaf(a2, b4.y, acc[2][1]);
      acc[2][2] = fmaf(a2, b4.z, acc[2][2]); acc[2][3] = fmaf(a2, b4.w, acc[2][3]);
      acc[3][0] = fmaf(a3, b4.x, acc[3][0]); acc[3][1] = fmaf(a3, b4.y, acc[3][1]);
      acc[3][2] = fmaf(a3, b4.z, acc[3][2]); acc[3][3] = fmaf(a3, b4.w, acc[3][3]);
    }
  }

  const float4 bo4 = *(const float4*)(bo + n0 + ng * 4);
#pragma unroll
  for (int jm = 0; jm < 4; ++jm) {
    int m = m0 + mg * 4 + jm;
    const float4 hv = *(const float4*)(hidden + (size_t)m * H_ + n0 + ng * 4);
    float4 o;
    o.x = acc[jm][0] + bo4.x + hv.x;
    o.y = acc[jm][1] + bo4.y + hv.y;
    o.z = acc[jm][2] + bo4.z + hv.z;
    o.w = acc[jm][3] + bo4.w + hv.w;
    *(float4*)(res + (size_t)m * H_ + n0 + ng * 4) = o;
  }
}

// ---------------------------------------------------------------------------
// K5: in-place LayerNorm over H=1024 per token (eps inside sqrt, as ref)
// ---------------------------------------------------------------------------
__global__ __launch_bounds__(256, 4) void k_layernorm(
    const float* __restrict__ gamma, const float* __restrict__ beta,
    float* __restrict__ out)
{
  const int t   = blockIdx.x;          // 4096 tokens
  const int tid = threadIdx.x;
  float4 x = *(const float4*)(out + (size_t)t * H_ + tid * 4);
  float s = x.x + x.y + x.z + x.w;
  float q = x.x * x.x + x.y * x.y + x.z * x.z + x.w * x.w;
  for (int off = 32; off > 0; off >>= 1) {
    s += __shfl_down(s, off, 64);
    q += __shfl_down(q, off, 64);
  }
  __shared__ float red[8];
  int wid = tid >> 6;
  if ((tid & 63) == 0) { red[wid] = s; red[4 + wid] = q; }
  __syncthreads();
  s = red[0] + red[1] + red[2] + red[3];
  q = red[4] + red[5] + red[6] + red[7];
  const float mu  = s * (1.f / 1024.f);
  const float var = fmaxf(q * (1.f / 1024.f) - mu * mu, 0.f);
  const float rstd = rsqrtf(var + 1e-12f);
  const float4 g4 = *(const float4*)(gamma + tid * 4);
  const float4 b4 = *(const float4*)(beta + tid * 4);
  float4 o;
  o.x = (x.x - mu) * rstd * g4.x + b4.x;
  o.y = (x.y - mu) * rstd * g4.y + b4.y;
  o.z = (x.z - mu) * rstd * g4.z + b4.z;
  o.w = (x.w - mu) * rstd * g4.w + b4.w;
  *(float4*)(out + (size_t)t * H_ + tid * 4) = o;
}

// ---------------------------------------------------------------------------
extern "C" void kernel_launch(void* const* d_in, const int* in_sizes, int n_in,
                              void* d_out, int out_size, void* d_ws, size_t ws_size,
                              hipStream_t stream) {
  (void)in_sizes; (void)n_in; (void)out_size; (void)ws_size;

  const float* hidden = (const float*)d_in[0];
  const float* Wq  = (const float*)d_in[1];  const float* bq = (const float*)d_in[2];
  const float* Wk  = (const float*)d_in[3];  const float* bk = (const float*)d_in[4];
  const float* Wv  = (const float*)d_in[5];  const float* bv = (const float*)d_in[6];
  const float* Uqr = (const float*)d_in[7];  const float* Uqi = (const float*)d_in[8];
  const float* Ukr = (const float*)d_in[9];  const float* Uki = (const float*)d_in[10];
  const float* Uvr = (const float*)d_in[11]; const float* Uvi = (const float*)d_in[12];
  const float* Wo  = (const float*)d_in[13]; const float* bo = (const float*)d_in[14];
  const float* gamma = (const float*)d_in[15];
  const float* beta  = (const float*)d_in[16];

  float* outp  = (float*)d_out;            // normed [B,S,H]
  float* probs = outp + NORMEDSZ;          // probs  [B,NH,S,S]

  float* ws = (float*)d_ws;
  ushort* qrP = (ushort*)(ws);                        // [32][2048][128] bf16
  ushort* qiP = (ushort*)(ws + (size_t)NELEM);
  ushort* krP = (ushort*)(ws + 2 * (size_t)NELEM);
  ushort* kiP = (ushort*)(ws + 3 * (size_t)NELEM);
  float*  vm  = ws + 4 * (size_t)NELEM;               // fp32 |v|
  float*  ls  = ws + 5 * (size_t)NELEM;               // [B*NH*S] row exp-sums
  float*  ctx = ws;                                   // alias: qrP dead after K2

  k_prep_gate<<<2048, 256, 0, stream>>>(hidden, Wq, bq, Wk, bk, Wv, bv,
                                        Uqr, Uqi, Ukr, Uki, Uvr, Uvi,
                                        qrP, qiP, krP, kiP, vm);
  k_scores_mfma<<<1024, 256, 0, stream>>>(qrP, qiP, krP, kiP, probs, ls);
  k_pv<<<1024, 256, 0, stream>>>(vm, ls, probs, ctx);
  k_out_gemm<<<1024, 256, 0, stream>>>(ctx, Wo, bo, hidden, outp);
  k_layernorm<<<4096, 256, 0, stream>>>(gamma, beta, outp);
}

// Round 2
// 1266.439 us; speedup vs baseline: 1.9514x; 1.2454x over previous
//
#include <hip/hip_runtime.h>
#include <math.h>

// QuantumAttention. B=2 S=2048 H=1024 NH=16 DH=64.
// Output = normed(4.19M) ++ probs(134.2M) fp32.
// This rev: k_pv moved to bf16 hi/lo MFMA (3 cross products ~ fp32 numerics).
// K1 emits |V| as transposed bf16 hi/lo planes [bh][d][s] for k_pv's B operand.
// Workspace (floats): qrP | qiP | krP | kiP (bf16 hi/lo packed, NELEM floats each)
//                     | vmP (hi plane NELEM ushorts + lo plane NELEM ushorts)
//                     | lsum  -> 5*4194304 + 65536 floats = 84.2 MB.
// K2 stores e=exp(score) into probs region; k_pv normalizes p = e * rinv.

#define B_  2
#define S_  2048
#define H_  1024
#define NH_ 16
#define DH_ 64
#define NELEM    4194304   // B*NH*S*DH
#define NORMEDSZ 4194304   // B*S*H

typedef __attribute__((ext_vector_type(8))) short bf16x8;
typedef __attribute__((ext_vector_type(8))) ushort u16x8;
typedef __attribute__((ext_vector_type(4))) float f32x4;

__device__ __forceinline__ ushort f2bf(float x) {   // RNE truncate to bf16
  uint u = __float_as_uint(x);
  u += 0x7fffu + ((u >> 16) & 1u);
  return (ushort)(u >> 16);
}
__device__ __forceinline__ float bf2f(ushort h) {
  return __uint_as_float(((uint)h) << 16);
}

// ---------------------------------------------------------------------------
// K1: per (b, h, 32-token tile): c = x@W+b ; (r,i)/=|.| ; complex rotate by U.
// q/k results written as bf16 hi/lo pairs (row layout [hi 64 | lo 64]);
// |v| written as transposed bf16 hi/lo planes vmH/vmL [bh][d][s].
// ---------------------------------------------------------------------------
__global__ __launch_bounds__(256, 4) void k_prep_gate(
    const float* __restrict__ hidden,
    const float* __restrict__ Wq, const float* __restrict__ bq,
    const float* __restrict__ Wk, const float* __restrict__ bk,
    const float* __restrict__ Wv, const float* __restrict__ bv,
    const float* __restrict__ Uqr, const float* __restrict__ Uqi,
    const float* __restrict__ Ukr, const float* __restrict__ Uki,
    const float* __restrict__ Uvr, const float* __restrict__ Uvi,
    ushort* __restrict__ qrP, ushort* __restrict__ qiP,
    ushort* __restrict__ krP, ushort* __restrict__ kiP,
    ushort* __restrict__ vmH, ushort* __restrict__ vmL)
{
  const int bid = blockIdx.x;          // 2*16*64 = 2048 blocks
  const int st  = bid & 63;
  const int h   = (bid >> 6) & 15;
  const int b   = bid >> 10;
  const int s0  = st * 32;
  const int tid = threadIdx.x;
  const int j   = tid & 63;
  const int tg  = tid >> 6;            // wave id: uniform -> LDS broadcast reads

  __shared__ float xs[32][64];
  __shared__ float rb[32][64];
  __shared__ float ib[32][64];

  for (int i = 0; i < 8; ++i) {
    int f = tid + i * 256;
    int t = f >> 6, d = f & 63;
    xs[t][d] = hidden[((b * S_ + s0 + t) * H_) + h * 64 + d];
  }
  __syncthreads();

  const float* Ws[3]  = {Wq, Wk, Wv};
  const float* bs[3]  = {bq, bk, bv};
  const float* Urs[3] = {Uqr, Ukr, Uvr};
  const float* Uis[3] = {Uqi, Uki, Uvi};
  const int bh   = b * NH_ + h;

  for (int m = 0; m < 3; ++m) {
    const float* W  = Ws[m];
    const float* bb = bs[m];
    const float* Ur = Urs[m];
    const float* Ui = Uis[m];

    float cr[8], ci[8];
    const float bj0 = bb[j], bj1 = bb[64 + j];
#pragma unroll
    for (int p = 0; p < 8; ++p) { cr[p] = bj0; ci[p] = bj1; }
    for (int d = 0; d < 64; ++d) {
      float wr = W[d * 128 + j];
      float wi = W[d * 128 + 64 + j];
#pragma unroll
      for (int p = 0; p < 8; ++p) {
        float x = xs[tg * 8 + p][d];
        cr[p] = fmaf(x, wr, cr[p]);
        ci[p] = fmaf(x, wi, ci[p]);
      }
    }
#pragma unroll
    for (int p = 0; p < 8; ++p) {
      float inv = rsqrtf(cr[p] * cr[p] + ci[p] * ci[p] + 1e-12f);
      rb[tg * 8 + p][j] = cr[p] * inv;
      ib[tg * 8 + p][j] = ci[p] * inv;
    }
    __syncthreads();

    float gr[8] = {0.f,0.f,0.f,0.f,0.f,0.f,0.f,0.f};
    float gi[8] = {0.f,0.f,0.f,0.f,0.f,0.f,0.f,0.f};
    for (int d = 0; d < 64; ++d) {
      float ur = Ur[d * 64 + j];
      float ui = Ui[d * 64 + j];
#pragma unroll
      for (int p = 0; p < 8; ++p) {
        float rv = rb[tg * 8 + p][d];
        float iv = ib[tg * 8 + p][d];
        gr[p] = fmaf(rv, ur, fmaf(-iv, ui, gr[p]));
        gi[p] = fmaf(rv, ui, fmaf( iv, ur, gi[p]));
      }
    }
    if (m == 2) {
      // |v| -> LDS (reuse rb), then transposed bf16 hi/lo global write
      __syncthreads();               // all waves done reading rb/ib
#pragma unroll
      for (int p = 0; p < 8; ++p)
        rb[tg * 8 + p][j] = sqrtf(gr[p] * gr[p] + gi[p] * gi[p]);
      __syncthreads();
      const int d  = tid >> 2;       // 0..63
      const int c4 = tid & 3;        // token chunk (8 tokens)
      u16x8 hv8, lv8;
#pragma unroll
      for (int tt = 0; tt < 8; ++tt) {
        float v = rb[c4 * 8 + tt][d];
        ushort hv = f2bf(v);
        hv8[tt] = hv;
        lv8[tt] = f2bf(v - bf2f(hv));
      }
      const size_t o = ((size_t)(bh * 64 + d)) * S_ + s0 + c4 * 8;
      *(u16x8*)(vmH + o) = hv8;
      *(u16x8*)(vmL + o) = lv8;
    } else {
      ushort* R = (m == 0) ? qrP : krP;
      ushort* I = (m == 0) ? qiP : kiP;
#pragma unroll
      for (int p = 0; p < 8; ++p) {
        int t = tg * 8 + p;
        size_t pb = (((size_t)bh) * S_ + (s0 + t)) * 128 + j;
        ushort hr = f2bf(gr[p]);
        R[pb]      = hr;
        R[pb + 64] = f2bf(gr[p] - bf2f(hr));
        ushort hi2 = f2bf(gi[p]);
        I[pb]      = hi2;
        I[pb + 64] = f2bf(gi[p] - bf2f(hi2));
      }
    }
    __syncthreads();  // rb/ib reused next stage
  }
}

// ---------------------------------------------------------------------------
// K2: complex QK^T via bf16 hi/lo MFMA (K=128 contraction per product pair),
// epilogue |.|*scale -> threshold -> e = exp(m) stored to probs region,
// per-row sum of e -> lsum.
// ---------------------------------------------------------------------------
#define MFMA16 __builtin_amdgcn_mfma_f32_16x16x32_bf16

__global__ __launch_bounds__(256, 2) void k_scores_mfma(
    const ushort* __restrict__ qrP, const ushort* __restrict__ qiP,
    const ushort* __restrict__ krP, const ushort* __restrict__ kiP,
    float* __restrict__ praw, float* __restrict__ lsum)
{
  // XCD-bijective swizzle: 1024 blocks -> 8 chunks of 128 (nwg % 8 == 0).
  const int bid0 = blockIdx.x;
  const int bid  = (bid0 & 7) * 128 + (bid0 >> 3);
  const int qt = bid & 31;
  const int bh = bid >> 5;
  const int q0 = qt * 64;
  const int tid  = threadIdx.x;
  const int lane = tid & 63;
  const int w    = tid >> 6;           // 4 waves
  const int wq   = w & 1;              // q half (32 rows)
  const int wk   = w >> 1;             // k half (32 cols)
  const int l15  = lane & 15;
  const int lg   = lane >> 4;          // 0..3

  __shared__ __align__(16) ushort skr[64 * 128];
  __shared__ __align__(16) ushort ski[64 * 128];
  __shared__ float lsh[64];
  if (tid < 64) lsh[tid] = 0.f;

  // Q fragments persistent in registers: rows q0+wq*32+rt*16+l15, d = ks*32+lg*8
  bf16x8 aqr[2][4], aqi[2][4];
#pragma unroll
  for (int rt = 0; rt < 2; ++rt) {
    const size_t ro = ((size_t)bh * S_ + q0 + wq * 32 + rt * 16 + l15) * 128 + lg * 8;
#pragma unroll
    for (int ks = 0; ks < 4; ++ks) {
      aqr[rt][ks] = *(const bf16x8*)(qrP + ro + ks * 32);
      aqi[rt][ks] = *(const bf16x8*)(qiP + ro + ks * 32);
    }
  }

  float esum[2][4] = {{0.f,0.f,0.f,0.f},{0.f,0.f,0.f,0.f}};

  const int swz = (l15 & 7) << 4;
  const int kbB = (wk * 32 + l15) * 256;   // LDS byte base of this lane's key row

  for (int kt = 0; kt < 32; ++kt) {
    __syncthreads();
    {   // stage kr/ki tile (64 keys x 128 d bf16 = 16KB each), swizzled
      const uint4* gr4 = (const uint4*)(krP + ((size_t)bh * S_ + kt * 64) * 128);
      const uint4* gi4 = (const uint4*)(kiP + ((size_t)bh * S_ + kt * 64) * 128);
#pragma unroll
      for (int i = 0; i < 4; ++i) {
        int c   = tid + i * 256;           // 1024 16B chunks
        int key = c >> 4;
        int dq  = c & 15;
        int dst = (key * 256 + dq * 16) ^ ((key & 7) << 4);
        *(uint4*)((char*)skr + dst) = gr4[c];
        *(uint4*)((char*)ski + dst) = gi4[c];
      }
    }
    __syncthreads();

    f32x4 aRR[2][2], aII[2][2], aRI[2][2], aIR[2][2];
#pragma unroll
    for (int rt = 0; rt < 2; ++rt)
#pragma unroll
      for (int ct = 0; ct < 2; ++ct) {
        aRR[rt][ct] = (f32x4){0.f,0.f,0.f,0.f};
        aII[rt][ct] = (f32x4){0.f,0.f,0.f,0.f};
        aRI[rt][ct] = (f32x4){0.f,0.f,0.f,0.f};
        aIR[rt][ct] = (f32x4){0.f,0.f,0.f,0.f};
      }

#pragma unroll
    for (int ks = 0; ks < 4; ++ks) {
#pragma unroll
      for (int ct = 0; ct < 2; ++ct) {
        const int o = kbB + ct * 4096 + ((ks * 64 + lg * 16) ^ swz);
        bf16x8 br = *(const bf16x8*)((const char*)skr + o);
        bf16x8 bi = *(const bf16x8*)((const char*)ski + o);
#pragma unroll
        for (int rt = 0; rt < 2; ++rt) {
          aRR[rt][ct] = MFMA16(aqr[rt][ks], br, aRR[rt][ct], 0, 0, 0);
          aIR[rt][ct] = MFMA16(aqi[rt][ks], br, aIR[rt][ct], 0, 0, 0);
          aRI[rt][ct] = MFMA16(aqr[rt][ks], bi, aRI[rt][ct], 0, 0, 0);
          aII[rt][ct] = MFMA16(aqi[rt][ks], bi, aII[rt][ct], 0, 0, 0);
        }
      }
    }

    // epilogue: sr/si -> |.|*0.125 -> threshold -> e = exp(m); store e
    const size_t rowb = ((size_t)bh * S_ + q0 + wq * 32) * S_
                      + (size_t)kt * 64 + wk * 32 + l15;
#pragma unroll
    for (int rt = 0; rt < 2; ++rt)
#pragma unroll
      for (int r = 0; r < 4; ++r) {
        const int rloc = rt * 16 + lg * 4 + r;
        float sr0 = aRR[rt][0][r] - aII[rt][0][r];
        float si0 = aRI[rt][0][r] + aIR[rt][0][r];
        float m0 = sqrtf(sr0 * sr0 + si0 * si0) * 0.125f;
        m0 = (m0 < 0.1f) ? 0.f : m0;
        float e0 = __expf(m0);
        float sr1 = aRR[rt][1][r] - aII[rt][1][r];
        float si1 = aRI[rt][1][r] + aIR[rt][1][r];
        float m1 = sqrtf(sr1 * sr1 + si1 * si1) * 0.125f;
        m1 = (m1 < 0.1f) ? 0.f : m1;
        float e1 = __expf(m1);
        praw[rowb + (size_t)rloc * S_]      = e0;
        praw[rowb + (size_t)rloc * S_ + 16] = e1;
        esum[rt][r] += e0 + e1;
      }
  }

  // reduce exp-sums: across the 16 lanes of each lg group, then across waves
#pragma unroll
  for (int rt = 0; rt < 2; ++rt)
#pragma unroll
    for (int r = 0; r < 4; ++r) {
      float v = esum[rt][r];
      v += __shfl_xor(v, 1, 64);
      v += __shfl_xor(v, 2, 64);
      v += __shfl_xor(v, 4, 64);
      v += __shfl_xor(v, 8, 64);
      if (l15 == 0) atomicAdd(&lsh[wq * 32 + rt * 16 + lg * 4 + r], v);
    }
  __syncthreads();
  if (tid < 64) lsum[(size_t)bh * S_ + q0 + tid] = lsh[tid];
}

// ---------------------------------------------------------------------------
// K3: p = e * (1/lsum), write normalized probs in-place, PV via bf16 hi/lo
// MFMA: ctx = P @ |V|. P tile [64q][64k] and V^T tile [64d][64k] in swizzled
// LDS (hi/lo planes). 4 waves in 2x2; 3 cross products for ~fp32 accuracy.
// ---------------------------------------------------------------------------
__global__ __launch_bounds__(256, 4) void k_pv_mfma(
    const ushort* __restrict__ vmH, const ushort* __restrict__ vmL,
    const float* __restrict__ lsum,
    float* __restrict__ probs, float* __restrict__ ctx)
{
  const int bid0 = blockIdx.x;         // 1024 = 32 bh * 32 qtiles
  const int bid  = (bid0 & 7) * 128 + (bid0 >> 3);   // XCD-bijective
  const int qt = bid & 31;
  const int bh = bid >> 5;
  const int q0 = qt * 64;
  const int b  = bh >> 4, h = bh & 15;
  const int tid  = threadIdx.x;
  const int lane = tid & 63;
  const int w    = tid >> 6;
  const int wq   = w & 1;              // q half (32 rows)
  const int wd   = w >> 1;             // d half (32 cols)
  const int l15  = lane & 15;
  const int lg   = lane >> 4;

  __shared__ __align__(16) ushort spH[64 * 64];   // P hi   [q][key]
  __shared__ __align__(16) ushort spL[64 * 64];   // P lo
  __shared__ __align__(16) ushort svH[64 * 64];   // V^T hi [d][key]
  __shared__ __align__(16) ushort svL[64 * 64];   // V^T lo
  __shared__ float rinv[64];
  if (tid < 64) rinv[tid] = 1.f / lsum[(size_t)bh * S_ + q0 + tid];

  f32x4 acc[2][2];
#pragma unroll
  for (int rt = 0; rt < 2; ++rt)
#pragma unroll
    for (int ct = 0; ct < 2; ++ct) acc[rt][ct] = (f32x4){0.f,0.f,0.f,0.f};

  const int swz = (l15 & 7) << 4;

  for (int kt = 0; kt < 32; ++kt) {
    __syncthreads();
    // normalize e tile -> write p to global -> bf16 hi/lo into swizzled LDS
#pragma unroll
    for (int i = 0; i < 4; ++i) {
      int f = tid + i * 256;           // 1024 float4 chunks
      int r = f >> 4, cq = f & 15;
      size_t off = ((size_t)bh * S_ + q0 + r) * S_ + kt * 64 + cq * 4;
      float4 e4 = *(const float4*)(probs + off);
      float ri = rinv[r];
      float4 p4;
      p4.x = e4.x * ri; p4.y = e4.y * ri; p4.z = e4.z * ri; p4.w = e4.w * ri;
      *(float4*)(probs + off) = p4;
      ushort h0 = f2bf(p4.x), h1 = f2bf(p4.y), h2 = f2bf(p4.z), h3 = f2bf(p4.w);
      uint2 hp, lp;
      hp.x = (uint)h0 | ((uint)h1 << 16);
      hp.y = (uint)h2 | ((uint)h3 << 16);
      lp.x = (uint)f2bf(p4.x - bf2f(h0)) | ((uint)f2bf(p4.y - bf2f(h1)) << 16);
      lp.y = (uint)f2bf(p4.z - bf2f(h2)) | ((uint)f2bf(p4.w - bf2f(h3)) << 16);
      int dst = (r * 128 + cq * 8) ^ ((r & 7) << 4);
      *(uint2*)((char*)spH + dst) = hp;
      *(uint2*)((char*)spL + dst) = lp;
    }
    // stage V^T tile: [64 d][64 keys] hi/lo, swizzled
#pragma unroll
    for (int i = 0; i < 4; ++i) {
      int c = tid + (i & 1) * 256;     // 512 16B chunks per plane
      int d = c >> 3, ch = c & 7;
      size_t src = ((size_t)(bh * 64 + d)) * S_ + kt * 64 + ch * 8;
      int dst = (d * 128 + ch * 16) ^ ((d & 7) << 4);
      if (i < 2) *(uint4*)((char*)svH + dst) = *(const uint4*)(vmH + src);
      else       *(uint4*)((char*)svL + dst) = *(const uint4*)(vmL + src);
    }
    __syncthreads();

#pragma unroll
    for (int ks = 0; ks < 2; ++ks) {   // 2 key-slices of 32
      const int co = (ks * 64 + lg * 16) ^ swz;
      bf16x8 aH[2], aL[2], bH[2], bL[2];
#pragma unroll
      for (int rt = 0; rt < 2; ++rt) {
        const int qrow = wq * 32 + rt * 16 + l15;
        aH[rt] = *(const bf16x8*)((const char*)spH + qrow * 128 + co);
        aL[rt] = *(const bf16x8*)((const char*)spL + qrow * 128 + co);
      }
#pragma unroll
      for (int ct = 0; ct < 2; ++ct) {
        const int drow = wd * 32 + ct * 16 + l15;
        bH[ct] = *(const bf16x8*)((const char*)svH + drow * 128 + co);
        bL[ct] = *(const bf16x8*)((const char*)svL + drow * 128 + co);
      }
#pragma unroll
      for (int rt = 0; rt < 2; ++rt)
#pragma unroll
        for (int ct = 0; ct < 2; ++ct) {
          acc[rt][ct] = MFMA16(aH[rt], bH[ct], acc[rt][ct], 0, 0, 0);
          acc[rt][ct] = MFMA16(aH[rt], bL[ct], acc[rt][ct], 0, 0, 0);
          acc[rt][ct] = MFMA16(aL[rt], bH[ct], acc[rt][ct], 0, 0, 0);
        }
    }
  }

  // C layout: col = l15, row = lg*4 + j (within each 16x16 tile)
#pragma unroll
  for (int rt = 0; rt < 2; ++rt)
#pragma unroll
    for (int ct = 0; ct < 2; ++ct)
#pragma unroll
      for (int j = 0; j < 4; ++j) {
        int q = q0 + wq * 32 + rt * 16 + lg * 4 + j;
        int dcol = h * 64 + wd * 32 + ct * 16 + l15;
        ctx[(size_t)(b * S_ + q) * H_ + dcol] = acc[rt][ct][j];
      }
}

// ---------------------------------------------------------------------------
// K4: res = ctx @ Wo + bo + hidden   (64x64 tile, K-tile 32, 4x4 micro)
// ---------------------------------------------------------------------------
#define AST 36
#define BST 68

__global__ __launch_bounds__(256, 4) void k_out_gemm(
    const float* __restrict__ ctx, const float* __restrict__ Wo,
    const float* __restrict__ bo, const float* __restrict__ hidden,
    float* __restrict__ res)
{
  const int bid = blockIdx.x;          // 64 mtiles * 16 ntiles = 1024
  const int nt  = bid & 15;
  const int mt  = bid >> 4;
  const int m0  = mt * 64, n0 = nt * 64;
  const int tid = threadIdx.x;
  const int mg  = tid >> 4, ng = tid & 15;

  __shared__ __align__(16) float sa[64 * AST];
  __shared__ __align__(16) float sb[32 * BST];

  float acc[4][4] = {{0.f,0.f,0.f,0.f},{0.f,0.f,0.f,0.f},
                     {0.f,0.f,0.f,0.f},{0.f,0.f,0.f,0.f}};

  for (int kt = 0; kt < 32; ++kt) {
    __syncthreads();
    for (int i = 0; i < 2; ++i) {      // a tile 64x32
      int g = tid + i * 256;
      int r = g >> 3, dq = g & 7;
      *(float4*)(sa + r * AST + dq * 4) =
          *(const float4*)(ctx + (size_t)(m0 + r) * H_ + kt * 32 + dq * 4);
    }
    for (int i = 0; i < 2; ++i) {      // b tile 32x64
      int g = tid + i * 256;
      int r = g >> 4, dq = g & 15;
      *(float4*)(sb + r * BST + dq * 4) =
          *(const float4*)(Wo + (size_t)(kt * 32 + r) * H_ + n0 + dq * 4);
    }
    __syncthreads();

    for (int kk = 0; kk < 32; ++kk) {
      const float4 b4 = *(const float4*)(sb + kk * BST + ng * 4);
      const float a0 = sa[(mg * 4 + 0) * AST + kk];
      const float a1 = sa[(mg * 4 + 1) * AST + kk];
      const float a2 = sa[(mg * 4 + 2) * AST + kk];
      const float a3 = sa[(mg * 4 + 3) * AST + kk];
      acc[0][0] = fmaf(a0, b4.x, acc[0][0]); acc[0][1] = fmaf(a0, b4.y, acc[0][1]);
      acc[0][2] = fmaf(a0, b4.z, acc[0][2]); acc[0][3] = fmaf(a0, b4.w, acc[0][3]);
      acc[1][0] = fmaf(a1, b4.x, acc[1][0]); acc[1][1] = fmaf(a1, b4.y, acc[1][1]);
      acc[1][2] = fmaf(a1, b4.z, acc[1][2]); acc[1][3] = fmaf(a1, b4.w, acc[1][3]);
      acc[2][0] = fmaf(a2, b4.x, acc[2][0]); acc[2][1] = fmaf(a2, b4.y, acc[2][1]);
      acc[2][2] = fmaf(a2, b4.z, acc[2][2]); acc[2][3] = fmaf(a2, b4.w, acc[2][3]);
      acc[3][0] = fmaf(a3, b4.x, acc[3][0]); acc[3][1] = fmaf(a3, b4.y, acc[3][1]);
      acc[3][2] = fmaf(a3, b4.z, acc[3][2]); acc[3][3] = fmaf(a3, b4.w, acc[3][3]);
    }
  }

  const float4 bo4 = *(const float4*)(bo + n0 + ng * 4);
#pragma unroll
  for (int jm = 0; jm < 4; ++jm) {
    int m = m0 + mg * 4 + jm;
    const float4 hv = *(const float4*)(hidden + (size_t)m * H_ + n0 + ng * 4);
    float4 o;
    o.x = acc[jm][0] + bo4.x + hv.x;
    o.y = acc[jm][1] + bo4.y + hv.y;
    o.z = acc[jm][2] + bo4.z + hv.z;
    o.w = acc[jm][3] + bo4.w + hv.w;
    *(float4*)(res + (size_t)m * H_ + n0 + ng * 4) = o;
  }
}

// ---------------------------------------------------------------------------
// K5: in-place LayerNorm over H=1024 per token (eps inside sqrt, as ref)
// ---------------------------------------------------------------------------
__global__ __launch_bounds__(256, 4) void k_layernorm(
    const float* __restrict__ gamma, const float* __restrict__ beta,
    float* __restrict__ out)
{
  const int t   = blockIdx.x;          // 4096 tokens
  const int tid = threadIdx.x;
  float4 x = *(const float4*)(out + (size_t)t * H_ + tid * 4);
  float s = x.x + x.y + x.z + x.w;
  float q = x.x * x.x + x.y * x.y + x.z * x.z + x.w * x.w;
  for (int off = 32; off > 0; off >>= 1) {
    s += __shfl_down(s, off, 64);
    q += __shfl_down(q, off, 64);
  }
  __shared__ float red[8];
  int wid = tid >> 6;
  if ((tid & 63) == 0) { red[wid] = s; red[4 + wid] = q; }
  __syncthreads();
  s = red[0] + red[1] + red[2] + red[3];
  q = red[4] + red[5] + red[6] + red[7];
  const float mu  = s * (1.f / 1024.f);
  const float var = fmaxf(q * (1.f / 1024.f) - mu * mu, 0.f);
  const float rstd = rsqrtf(var + 1e-12f);
  const float4 g4 = *(const float4*)(gamma + tid * 4);
  const float4 b4 = *(const float4*)(beta + tid * 4);
  float4 o;
  o.x = (x.x - mu) * rstd * g4.x + b4.x;
  o.y = (x.y - mu) * rstd * g4.y + b4.y;
  o.z = (x.z - mu) * rstd * g4.z + b4.z;
  o.w = (x.w - mu) * rstd * g4.w + b4.w;
  *(float4*)(out + (size_t)t * H_ + tid * 4) = o;
}

// ---------------------------------------------------------------------------
extern "C" void kernel_launch(void* const* d_in, const int* in_sizes, int n_in,
                              void* d_out, int out_size, void* d_ws, size_t ws_size,
                              hipStream_t stream) {
  (void)in_sizes; (void)n_in; (void)out_size; (void)ws_size;

  const float* hidden = (const float*)d_in[0];
  const float* Wq  = (const float*)d_in[1];  const float* bq = (const float*)d_in[2];
  const float* Wk  = (const float*)d_in[3];  const float* bk = (const float*)d_in[4];
  const float* Wv  = (const float*)d_in[5];  const float* bv = (const float*)d_in[6];
  const float* Uqr = (const float*)d_in[7];  const float* Uqi = (const float*)d_in[8];
  const float* Ukr = (const float*)d_in[9];  const float* Uki = (const float*)d_in[10];
  const float* Uvr = (const float*)d_in[11]; const float* Uvi = (const float*)d_in[12];
  const float* Wo  = (const float*)d_in[13]; const float* bo = (const float*)d_in[14];
  const float* gamma = (const float*)d_in[15];
  const float* beta  = (const float*)d_in[16];

  float* outp  = (float*)d_out;            // normed [B,S,H]
  float* probs = outp + NORMEDSZ;          // probs  [B,NH,S,S]

  float* ws = (float*)d_ws;
  ushort* qrP = (ushort*)(ws);                        // [32][2048][hi64|lo64] bf16
  ushort* qiP = (ushort*)(ws + (size_t)NELEM);
  ushort* krP = (ushort*)(ws + 2 * (size_t)NELEM);
  ushort* kiP = (ushort*)(ws + 3 * (size_t)NELEM);
  ushort* vmH = (ushort*)(ws + 4 * (size_t)NELEM);    // V^T hi [32][64][2048]
  ushort* vmL = vmH + (size_t)NELEM;                  // V^T lo
  float*  ls  = ws + 5 * (size_t)NELEM;               // [B*NH*S] row exp-sums
  float*  ctx = ws;                                   // alias: qrP dead after k_pv

  k_prep_gate<<<2048, 256, 0, stream>>>(hidden, Wq, bq, Wk, bk, Wv, bv,
                                        Uqr, Uqi, Ukr, Uki, Uvr, Uvi,
                                        qrP, qiP, krP, kiP, vmH, vmL);
  k_scores_mfma<<<1024, 256, 0, stream>>>(qrP, qiP, krP, kiP, probs, ls);
  k_pv_mfma<<<1024, 256, 0, stream>>>(vmH, vmL, ls, probs, ctx);
  k_out_gemm<<<1024, 256, 0, stream>>>(ctx, Wo, bo, hidden, outp);
  k_layernorm<<<4096, 256, 0, stream>>>(gamma, beta, outp);
}